// Round 4
// baseline (534.266 us; speedup 1.0000x reference)
//
#include <hip/hip_runtime.h>
#include <hip/hip_bf16.h>
#include <math.h>

// ============ ROUND 4: ATTRIBUTION ABLATION ============
// Identical kernels to R3. The launch sequence runs the FULL pipeline TWICE
// (second copy re-derives everything from the inputs; output written twice
// with equal values). T_new - 382 = sum of all kernel durations (warm).
// =======================================================

#define N_NODES 40000
#define N_EDGES 1280000
#define D_FEAT 1024
#define HIDDEN 64
#define N_CLASSES 40
#define NB 157            // buckets of 256 destination cols: ceil(40000/256)
#define CHUNK 4096        // edges per k_binscatter block (16 per thread)

typedef _Float16 f16x8 __attribute__((ext_vector_type(8)));
typedef float f32x4 __attribute__((ext_vector_type(4)));

// ---------------- fused pass 0: bucket histogram + W1 transpose/convert ----------------

#define HIST_BLOCKS 313   // ceil(1280000/4096)
#define CONV_BLOCKS 256   // 65536/256

__global__ __launch_bounds__(256) void k_pre(const int* __restrict__ col,
                                             int* __restrict__ btot,
                                             const float* __restrict__ W,
                                             _Float16* __restrict__ Wt) {
    __shared__ int h[NB];
    int tid = threadIdx.x;
    if (blockIdx.x < HIST_BLOCKS) {
        if (tid < NB) h[tid] = 0;
        __syncthreads();
        int e0 = blockIdx.x * 4096;
        int e1 = min(e0 + 4096, N_EDGES);
        for (int e = e0 + tid; e < e1; e += 256)
            atomicAdd(&h[col[e] >> 8], 1);
        __syncthreads();
        if (tid < NB && h[tid]) atomicAdd(&btot[tid], h[tid]);
    } else {
        int i = (blockIdx.x - HIST_BLOCKS) * 256 + tid;
        int n = i & 63, k = i >> 6;
        Wt[n * D_FEAT + k] = (_Float16)W[k * HIDDEN + n];
    }
}

// ---------------- pass 1: bin edges, bucket-ordered in LDS, coalesced flush ----------------
// sedge element: (col&255)<<16 | row   (row < 40000 < 2^16)

__global__ __launch_bounds__(256) void k_binscatter(const int* __restrict__ row,
                                                    const int* __restrict__ col,
                                                    const int* __restrict__ btot,
                                                    int* __restrict__ gcur,
                                                    unsigned* __restrict__ sedge) {
    __shared__ unsigned stage[CHUNK];
    __shared__ unsigned char bo[CHUNK];
    __shared__ int sc[256];
    __shared__ int bb[NB];
    __shared__ int hist[NB];
    __shared__ int lo[NB];
    __shared__ int cur[NB];
    __shared__ int dst[NB];
    const int tid = threadIdx.x;
    const int e0 = blockIdx.x * CHUNK;
    const int nE = min(CHUNK, N_EDGES - e0);

    if (tid < NB) { hist[tid] = 0; cur[tid] = 0; }
    int bv = (tid < NB) ? btot[tid] : 0;
    sc[tid] = bv;
    __syncthreads();
#pragma unroll
    for (int d = 1; d < 256; d <<= 1) {
        int t = (tid >= d) ? sc[tid - d] : 0;
        __syncthreads();
        sc[tid] += t;
        __syncthreads();
    }
    if (tid < NB) bb[tid] = sc[tid] - bv;   // exclusive bucket base (global)

    int c[16];
#pragma unroll
    for (int t = 0; t < 16; ++t) {
        int e = tid + t * 256;
        c[t] = (e < nE) ? col[e0 + e] : -1;
        if (e < nE) atomicAdd(&hist[c[t] >> 8], 1);
    }
    __syncthreads();

    int hv = (tid < NB) ? hist[tid] : 0;
    sc[tid] = hv;
    __syncthreads();
#pragma unroll
    for (int d = 1; d < 256; d <<= 1) {
        int t = (tid >= d) ? sc[tid - d] : 0;
        __syncthreads();
        sc[tid] += t;
        __syncthreads();
    }
    if (tid < NB) {
        int excl = sc[tid] - hv;
        lo[tid] = excl;
        int cp = hv ? atomicAdd(&gcur[tid], hv) : 0;
        dst[tid] = bb[tid] + cp - excl;     // global addr = dst[b] + ldsIdx
    }
    __syncthreads();

#pragma unroll
    for (int t = 0; t < 16; ++t) {
        int e = tid + t * 256;
        if (e < nE) {
            int b = c[t] >> 8;
            int p = lo[b] + atomicAdd(&cur[b], 1);
            stage[p] = ((unsigned)(c[t] & 255) << 16) | (unsigned)row[e0 + e];
            bo[p] = (unsigned char)b;
        }
    }
    __syncthreads();
    for (int i = tid; i < nE; i += 256)
        sedge[dst[bo[i]] + i] = stage[i];   // coalesced: consecutive i -> consecutive addr per run
}

// ---------------- pass 2: per-bucket counting sort; emits off[], dinv[], sorted[] (u16) ----------------

__global__ __launch_bounds__(256) void k_bucketsort(const unsigned* __restrict__ sedge,
                                                    const int* __restrict__ btot,
                                                    int* __restrict__ off,
                                                    float* __restrict__ dinv,
                                                    unsigned short* __restrict__ sorted) {
    __shared__ int sc[256];
    __shared__ int hist[256];
    __shared__ int cur[256];
    const int tid = threadIdx.x;
    const int b = blockIdx.x;
    int bv = (tid < NB) ? btot[tid] : 0;
    sc[tid] = bv;
    hist[tid] = 0;
    __syncthreads();
#pragma unroll
    for (int d = 1; d < 256; d <<= 1) {
        int t = (tid >= d) ? sc[tid - d] : 0;
        __syncthreads();
        sc[tid] += t;
        __syncthreads();
    }
    const int base = (b == 0) ? 0 : sc[b - 1];
    const int end  = sc[b];
    __syncthreads();

    for (int i = base + tid; i < end; i += 256)
        atomicAdd(&hist[sedge[i] >> 16], 1);
    __syncthreads();
    int v = hist[tid];
    sc[tid] = v;
    __syncthreads();
#pragma unroll
    for (int d = 1; d < 256; d <<= 1) {
        int t = (tid >= d) ? sc[tid - d] : 0;
        __syncthreads();
        sc[tid] += t;
        __syncthreads();
    }
    int excl = sc[tid] - v;
    cur[tid] = excl;
    int col0 = b << 8;
    int ncol = min(256, N_NODES - col0);
    if (tid < ncol) {
        off[col0 + tid] = base + excl;
        dinv[col0 + tid] = rsqrtf((float)(v + 1));   // +1 self-loop
    }
    if (b == NB - 1 && tid == 0) off[N_NODES] = N_EDGES;
    __syncthreads();
    for (int i = base + tid; i < end; i += 256) {
        unsigned e = sedge[i];
        int p = atomicAdd(&cur[e >> 16], 1);
        sorted[base + p] = (unsigned short)e;
    }
}

// ---------------- GEMM1 v2 (f16 MFMA): 64x64 tile, double-buffered LDS, reg prefetch ----------
// hs1[i,j] = f16((x[i,:] @ W1[:,j]) * dinv[i]); 625 blocks, 1 barrier per K-iter.

#define LDA 72
#define LDB 72

__global__ __launch_bounds__(256) void k_gemm1(const float* __restrict__ X,
                                               const _Float16* __restrict__ Wt,
                                               const float* __restrict__ dinv,
                                               _Float16* __restrict__ out) {
    __shared__ _Float16 As[2][64 * LDA];
    __shared__ _Float16 Bs[2][64 * LDB];
    const int tid = threadIdx.x;
    const int wave = tid >> 6, lane = tid & 63;
    const int row0 = blockIdx.x * 64;
    const int m0 = (wave & 1) * 32, n0 = (wave >> 1) * 32;
    const int lr = lane & 15, quad = lane >> 4;

    const int ar = tid >> 2;          // 0..63 A row
    const int ak = (tid & 3) * 16;    // K offset (16 floats, 64 B contiguous)
    const int bn = tid >> 2;          // 0..63 B row (n)
    const int bk = (tid & 3) * 16;    // K offset (16 halves)

    f32x4 acc00 = {0.f,0.f,0.f,0.f}, acc01 = {0.f,0.f,0.f,0.f};
    f32x4 acc10 = {0.f,0.f,0.f,0.f}, acc11 = {0.f,0.f,0.f,0.f};

    float4 xv0, xv1, xv2, xv3;
    uint4 wv0, wv1;

#define GLOAD(K0) {                                                          \
        const float4* xp = (const float4*)&X[(row0 + ar) * D_FEAT + (K0) + ak]; \
        xv0 = xp[0]; xv1 = xp[1]; xv2 = xp[2]; xv3 = xp[3];                  \
        const uint4* wp = (const uint4*)&Wt[bn * D_FEAT + (K0) + bk];        \
        wv0 = wp[0]; wv1 = wp[1]; }

#define LSTORE(B) {                                                          \
        f16x8 p0 = {(_Float16)xv0.x,(_Float16)xv0.y,(_Float16)xv0.z,(_Float16)xv0.w, \
                    (_Float16)xv1.x,(_Float16)xv1.y,(_Float16)xv1.z,(_Float16)xv1.w}; \
        f16x8 p1 = {(_Float16)xv2.x,(_Float16)xv2.y,(_Float16)xv2.z,(_Float16)xv2.w, \
                    (_Float16)xv3.x,(_Float16)xv3.y,(_Float16)xv3.z,(_Float16)xv3.w}; \
        *(f16x8*)&As[B][ar * LDA + ak]     = p0;                             \
        *(f16x8*)&As[B][ar * LDA + ak + 8] = p1;                             \
        *(uint4*)&Bs[B][bn * LDB + bk]     = wv0;                            \
        *(uint4*)&Bs[B][bn * LDB + bk + 8] = wv1; }

#define MFMA_STEP(B) {                                                       \
        _Pragma("unroll")                                                    \
        for (int kk = 0; kk < 64; kk += 32) {                                \
            f16x8 a0 = *(f16x8*)&As[B][(m0 + lr) * LDA + kk + quad * 8];     \
            f16x8 a1 = *(f16x8*)&As[B][(m0 + 16 + lr) * LDA + kk + quad * 8];\
            f16x8 b0 = *(f16x8*)&Bs[B][(n0 + lr) * LDB + kk + quad * 8];     \
            f16x8 b1 = *(f16x8*)&Bs[B][(n0 + 16 + lr) * LDB + kk + quad * 8];\
            acc00 = __builtin_amdgcn_mfma_f32_16x16x32_f16(a0, b0, acc00, 0, 0, 0); \
            acc01 = __builtin_amdgcn_mfma_f32_16x16x32_f16(a0, b1, acc01, 0, 0, 0); \
            acc10 = __builtin_amdgcn_mfma_f32_16x16x32_f16(a1, b0, acc10, 0, 0, 0); \
            acc11 = __builtin_amdgcn_mfma_f32_16x16x32_f16(a1, b1, acc11, 0, 0, 0); \
        } }

    GLOAD(0);
    LSTORE(0);
    __syncthreads();
    int buf = 0;
    for (int k0 = 64; k0 < D_FEAT; k0 += 64) {
        GLOAD(k0);              // issue next-tile loads early (hide under MFMA)
        MFMA_STEP(buf);
        LSTORE(buf ^ 1);        // waits on loads, writes other buffer
        __syncthreads();
        buf ^= 1;
    }
    MFMA_STEP(buf);

#pragma unroll
    for (int r = 0; r < 4; ++r) {
        int m = row0 + m0 + quad * 4 + r;
        float dv0 = dinv[m], dv1 = dinv[m + 16];
        out[m * HIDDEN + n0 + lr]             = (_Float16)(acc00[r] * dv0);
        out[m * HIDDEN + n0 + 16 + lr]        = (_Float16)(acc01[r] * dv0);
        out[(m + 16) * HIDDEN + n0 + lr]      = (_Float16)(acc10[r] * dv1);
        out[(m + 16) * HIDDEN + n0 + 16 + lr] = (_Float16)(acc11[r] * dv1);
    }
#undef GLOAD
#undef LSTORE
#undef MFMA_STEP
}

// ---------------- gather1: A1[node] = f16( dinv * relu(dinv * agg(B1) + b1) ) ----------------

__global__ __launch_bounds__(256) void k_agg1(const int* __restrict__ off,
                                              const unsigned short* __restrict__ sorted,
                                              const _Float16* __restrict__ hs,
                                              const float* __restrict__ dinv,
                                              const float* __restrict__ bias,
                                              _Float16* __restrict__ A1) {
    const int tid = threadIdx.x;
    const int wave = tid >> 6, lane = tid & 63;
    const int node = blockIdx.x * 4 + wave;
    const int g = lane >> 3;      // edge slot within a 16-edge step
    const int sl = lane & 7;      // feature slice (8 f16 = 16 B)

    float acc[8];
#pragma unroll
    for (int j = 0; j < 8; ++j) acc[j] = 0.f;
    if (g == 0) {                 // self-loop counted exactly once (group 0)
        f16x8 v = *(const f16x8*)&hs[node * HIDDEN + sl * 8];
#pragma unroll
        for (int j = 0; j < 8; ++j) acc[j] = (float)v[j];
    }

    const int beg = off[node], end = off[node + 1];
    for (int base = beg; base < end; base += 64) {
        int m = end - base; if (m > 64) m = 64;
        int vidx = (lane < m) ? (int)sorted[base + lane] : 0;
        int nfull = m & ~15;
        int i = 0;
        for (; i < nfull; i += 16) {          // 16 edges, 2 loads/lane in flight
            int s0 = __shfl(vidx, i + g, 64);
            int s1 = __shfl(vidx, i + 8 + g, 64);
            f16x8 v0 = *(const f16x8*)&hs[s0 * HIDDEN + sl * 8];
            f16x8 v1 = *(const f16x8*)&hs[s1 * HIDDEN + sl * 8];
            f16x8 t = v0 + v1;                // v_pk_add_f16 x4
#pragma unroll
            for (int j = 0; j < 8; ++j)
                acc[j] += (float)t[j];
        }
        if (i < m) {                          // masked tail (<16 edges)
            int s0 = __shfl(vidx, i + g, 64);
            int s1 = __shfl(vidx, i + 8 + g, 64);   // i+8+g <= 63 always
            f16x8 v0 = {};
            f16x8 v1 = {};
            if (i + g < m)     v0 = *(const f16x8*)&hs[s0 * HIDDEN + sl * 8];
            if (i + 8 + g < m) v1 = *(const f16x8*)&hs[s1 * HIDDEN + sl * 8];
            f16x8 t = v0 + v1;
#pragma unroll
            for (int j = 0; j < 8; ++j)
                acc[j] += (float)t[j];
        }
    }

    // fold the 8 edge-groups (bits 3..5 of lane)
#pragma unroll
    for (int j = 0; j < 8; ++j) {
        acc[j] += __shfl_xor(acc[j], 8, 64);
        acc[j] += __shfl_xor(acc[j], 16, 64);
        acc[j] += __shfl_xor(acc[j], 32, 64);
    }
    if (lane < 8) {
        float dv = dinv[node];
        f16x8 o;
#pragma unroll
        for (int j = 0; j < 8; ++j) {
            float z = fmaf(dv, acc[j], bias[lane * 8 + j]);
            o[j] = (_Float16)(fmaxf(z, 0.f) * dv);   // pre-scale for layer-2 source norm
        }
        *(f16x8*)&A1[node * HIDDEN + lane * 8] = o;
    }
}

// ---------------- gather2 + GEMV(64x40) + log-softmax ----------------

__global__ __launch_bounds__(256) void k_agg2_lsm(const int* __restrict__ off,
                                                  const unsigned short* __restrict__ sorted,
                                                  const _Float16* __restrict__ A1,
                                                  const float* __restrict__ dinv,
                                                  const float* __restrict__ b2,
                                                  const float* __restrict__ W2,
                                                  float* __restrict__ out) {
    __shared__ float W2s[HIDDEN * N_CLASSES];   // [k][c], as given
    __shared__ float aggs[4][HIDDEN];
    const int tid = threadIdx.x;
    for (int i = tid; i < HIDDEN * N_CLASSES; i += 256) W2s[i] = W2[i];
    const int wave = tid >> 6, lane = tid & 63;
    const int node = blockIdx.x * 4 + wave;
    const int g = lane >> 3, sl = lane & 7;

    float acc[8];
#pragma unroll
    for (int j = 0; j < 8; ++j) acc[j] = 0.f;
    if (g == 0) {
        f16x8 v = *(const f16x8*)&A1[node * HIDDEN + sl * 8];
#pragma unroll
        for (int j = 0; j < 8; ++j) acc[j] = (float)v[j];
    }
    __syncthreads();   // W2s staged; placed before divergent-length gather

    const int beg = off[node], end = off[node + 1];
    for (int base = beg; base < end; base += 64) {
        int m = end - base; if (m > 64) m = 64;
        int vidx = (lane < m) ? (int)sorted[base + lane] : 0;
        int nfull = m & ~15;
        int i = 0;
        for (; i < nfull; i += 16) {
            int s0 = __shfl(vidx, i + g, 64);
            int s1 = __shfl(vidx, i + 8 + g, 64);
            f16x8 v0 = *(const f16x8*)&A1[s0 * HIDDEN + sl * 8];
            f16x8 v1 = *(const f16x8*)&A1[s1 * HIDDEN + sl * 8];
            f16x8 t = v0 + v1;
#pragma unroll
            for (int j = 0; j < 8; ++j)
                acc[j] += (float)t[j];
        }
        if (i < m) {
            int s0 = __shfl(vidx, i + g, 64);
            int s1 = __shfl(vidx, i + 8 + g, 64);
            f16x8 v0 = {};
            f16x8 v1 = {};
            if (i + g < m)     v0 = *(const f16x8*)&A1[s0 * HIDDEN + sl * 8];
            if (i + 8 + g < m) v1 = *(const f16x8*)&A1[s1 * HIDDEN + sl * 8];
            f16x8 t = v0 + v1;
#pragma unroll
            for (int j = 0; j < 8; ++j)
                acc[j] += (float)t[j];
        }
    }
#pragma unroll
    for (int j = 0; j < 8; ++j) {
        acc[j] += __shfl_xor(acc[j], 8, 64);
        acc[j] += __shfl_xor(acc[j], 16, 64);
        acc[j] += __shfl_xor(acc[j], 32, 64);
    }
    if (lane < 8) {
        f32x4 t0 = {acc[0], acc[1], acc[2], acc[3]};
        f32x4 t1 = {acc[4], acc[5], acc[6], acc[7]};
        *(f32x4*)&aggs[wave][lane * 8]     = t0;
        *(f32x4*)&aggs[wave][lane * 8 + 4] = t1;
    }
    __builtin_amdgcn_wave_barrier();   // same-wave LDS write->read ordering fence

    float z = -INFINITY;
    if (lane < N_CLASSES) {
        float s = 0.f;
        const float* ag = aggs[wave];
#pragma unroll
        for (int k = 0; k < HIDDEN; ++k)
            s = fmaf(ag[k], W2s[k * N_CLASSES + lane], s);
        z = fmaf(dinv[node], s, b2[lane]);
    }
    float mv = z;
#pragma unroll
    for (int d = 32; d > 0; d >>= 1) mv = fmaxf(mv, __shfl_xor(mv, d, 64));
    float ex = (lane < N_CLASSES) ? expf(z - mv) : 0.f;
#pragma unroll
    for (int d = 32; d > 0; d >>= 1) ex += __shfl_xor(ex, d, 64);
    float lse = mv + logf(ex);
    if (lane < N_CLASSES) out[node * N_CLASSES + lane] = z - lse;
}

// ---------------- launch: FULL PIPELINE TWICE (ablation) ----------------

extern "C" void kernel_launch(void* const* d_in, const int* in_sizes, int n_in,
                              void* d_out, int out_size, void* d_ws, size_t ws_size,
                              hipStream_t stream) {
    const float* x  = (const float*)d_in[0];
    const int*   ei = (const int*)d_in[1];
    const float* W1 = (const float*)d_in[2];
    const float* b1 = (const float*)d_in[3];
    const float* W2 = (const float*)d_in[4];
    const float* b2 = (const float*)d_in[5];
    const int* row = ei;             // edge_index[0] = source
    const int* col = ei + N_EDGES;   // edge_index[1] = target

    char* ws = (char*)d_ws;
    int*            btot   = (int*)(ws + 0);             // 628 B
    int*            gcur   = (int*)(ws + 1024);          // 628 B
    int*            off    = (int*)(ws + 4096);          // 160 KB + 4
    float*          dinv   = (float*)(ws + 167936);      // 160 KB
    unsigned*       sedge  = (unsigned*)(ws + 335872);   // 5.12 MB (dead after bucketsort)
    unsigned short* sorted = (unsigned short*)(ws + 5455872); // 2.56 MB
    _Float16*       W1t    = (_Float16*)(ws + 8015872);  // 128 KB
    _Float16*       B1     = (_Float16*)(ws + 8146944);  // 5.12 MB : hs1 f16
    _Float16*       A1     = (_Float16*)(ws + 335872);   // 5.12 MB : reuse sedge slot

    for (int rep = 0; rep < 2; ++rep) {
        hipMemsetAsync(btot, 0, 2048, stream);   // btot + gcur (makes binscatter re-runnable)
        k_pre<<<HIST_BLOCKS + CONV_BLOCKS, 256, 0, stream>>>(col, btot, W1, W1t);
        k_binscatter<<<(N_EDGES + CHUNK - 1) / CHUNK, 256, 0, stream>>>(row, col, btot, gcur, sedge);
        k_bucketsort<<<NB, 256, 0, stream>>>(sedge, btot, off, dinv, sorted);

        k_gemm1<<<N_NODES / 64, 256, 0, stream>>>(x, W1t, dinv, B1);
        k_agg1<<<N_NODES / 4, 256, 0, stream>>>(off, sorted, B1, dinv, b1, A1);
        k_agg2_lsm<<<N_NODES / 4, 256, 0, stream>>>(off, sorted, A1, dinv, b2, W2, (float*)d_out);
    }
}

// Round 5
// 370.340 us; speedup vs baseline: 1.4426x; 1.4426x over previous
//
#include <hip/hip_runtime.h>
#include <hip/hip_bf16.h>
#include <math.h>

#define N_NODES 40000
#define N_EDGES 1280000
#define D_FEAT 1024
#define HIDDEN 64
#define N_CLASSES 40
#define NB 157            // buckets of 256 destination cols: ceil(40000/256)
#define CHUNK 2048        // edges per k_binscatter block (8 per thread; 625*2048 == N_EDGES)
#define SORT_STAGE 10240  // u16 staging capacity in k_bucketsort (expected max bucket ~8500)

typedef _Float16 f16x8 __attribute__((ext_vector_type(8)));
typedef float f32x4 __attribute__((ext_vector_type(4)));

// wave-level inclusive scan (64 lanes, 6 shfl steps, no barriers)
__device__ __forceinline__ int wscan64(int v, int lane) {
#pragma unroll
    for (int d = 1; d < 64; d <<= 1) {
        int t = __shfl_up(v, d, 64);
        v += (lane >= d) ? t : 0;
    }
    return v;
}

// ---------------- fused pass 0: bucket histogram (int4) + W1 transpose/convert ----------------

#define HIST_BLOCKS 313   // 313 * 4096 >= N_EDGES
#define CONV_BLOCKS 256   // 65536/256

__global__ __launch_bounds__(256) void k_pre(const int* __restrict__ col,
                                             int* __restrict__ btot,
                                             const float* __restrict__ W,
                                             _Float16* __restrict__ Wt) {
    __shared__ int h[NB];
    int tid = threadIdx.x;
    if (blockIdx.x < HIST_BLOCKS) {
        if (tid < NB) h[tid] = 0;
        __syncthreads();
        int e0 = blockIdx.x * 4096;
#pragma unroll
        for (int t = 0; t < 4; ++t) {
            int e = e0 + t * 1024 + tid * 4;
            if (e < N_EDGES) {                      // N_EDGES%4==0, e%4==0 -> int4 safe
                int4 c = *(const int4*)&col[e];
                atomicAdd(&h[c.x >> 8], 1);
                atomicAdd(&h[c.y >> 8], 1);
                atomicAdd(&h[c.z >> 8], 1);
                atomicAdd(&h[c.w >> 8], 1);
            }
        }
        __syncthreads();
        if (tid < NB && h[tid]) atomicAdd(&btot[tid], h[tid]);
    } else {
        int i = (blockIdx.x - HIST_BLOCKS) * 256 + tid;
        int n = i & 63, k = i >> 6;
        Wt[n * D_FEAT + k] = (_Float16)W[k * HIDDEN + n];
    }
}

// ---------------- tiny: exclusive scan of btot -> bb (global bucket bases) ----------------

__global__ __launch_bounds__(256) void k_scanbb(const int* __restrict__ btot,
                                                int* __restrict__ bb) {
    __shared__ int wsum[4];
    const int tid = threadIdx.x;
    const int wave = tid >> 6, lane = tid & 63;
    int v = (tid < NB) ? btot[tid] : 0;
    int iv = wscan64(v, lane);
    if (lane == 63) wsum[wave] = iv;
    __syncthreads();
    int add = 0;
#pragma unroll
    for (int w = 0; w < 3; ++w)
        add += (w < wave) ? wsum[w] : 0;
    if (tid < NB) bb[tid] = iv + add - v;   // exclusive
}

// ---------------- pass 1: bin edges, bucket-ordered in LDS, coalesced flush ----------------
// sedge element: (col&255)<<16 | row   (row < 40000 < 2^16)

__global__ __launch_bounds__(256) void k_binscatter(const int* __restrict__ row,
                                                    const int* __restrict__ col,
                                                    const int* __restrict__ bb,
                                                    int* __restrict__ gcur,
                                                    unsigned* __restrict__ sedge) {
    __shared__ unsigned stage[CHUNK];
    __shared__ unsigned char bo[CHUNK];
    __shared__ int hist[NB];
    __shared__ int lo[NB];
    __shared__ int cur[NB];
    __shared__ int dst[NB];
    __shared__ int wsum[4];
    const int tid = threadIdx.x;
    const int wave = tid >> 6, lane = tid & 63;
    const int e0 = blockIdx.x * CHUNK;      // 625 blocks * 2048 == N_EDGES, no bounds checks

    if (tid < NB) { hist[tid] = 0; cur[tid] = 0; }
    __syncthreads();

    int c[8];
#pragma unroll
    for (int t = 0; t < 8; ++t) {
        int e = tid + t * 256;
        c[t] = col[e0 + e];
        atomicAdd(&hist[c[t] >> 8], 1);
    }
    __syncthreads();

    // wave-shfl scan of hist[0..NB)
    int hv = (tid < NB) ? hist[tid] : 0;
    int iv = wscan64(hv, lane);
    if (lane == 63) wsum[wave] = iv;
    __syncthreads();
    int add = 0;
#pragma unroll
    for (int w = 0; w < 3; ++w)
        add += (w < wave) ? wsum[w] : 0;
    if (tid < NB) {
        int excl = iv + add - hv;
        lo[tid] = excl;
        int cp = hv ? atomicAdd(&gcur[tid], hv) : 0;
        dst[tid] = bb[tid] + cp - excl;     // global addr = dst[b] + ldsIdx
    }
    __syncthreads();

#pragma unroll
    for (int t = 0; t < 8; ++t) {
        int e = tid + t * 256;
        int b = c[t] >> 8;
        int p = lo[b] + atomicAdd(&cur[b], 1);
        stage[p] = ((unsigned)(c[t] & 255) << 16) | (unsigned)row[e0 + e];
        bo[p] = (unsigned char)b;
    }
    __syncthreads();
    for (int i = tid; i < CHUNK; i += 256)
        sedge[dst[bo[i]] + i] = stage[i];   // coalesced: consecutive i -> consecutive addr per run
}

// ---------------- pass 2: per-bucket counting sort; LDS-staged coalesced output ----------------

__global__ __launch_bounds__(512) void k_bucketsort(const unsigned* __restrict__ sedge,
                                                    const int* __restrict__ btot,
                                                    const int* __restrict__ bb,
                                                    int* __restrict__ off,
                                                    float* __restrict__ dinv,
                                                    unsigned short* __restrict__ sorted) {
    __shared__ int hist[256];
    __shared__ int cur[256];
    __shared__ unsigned short st[SORT_STAGE];
    __shared__ int wsum[4];
    const int tid = threadIdx.x;
    const int wave = tid >> 6, lane = tid & 63;
    const int b = blockIdx.x;
    const int base = bb[b];
    const int cnt  = btot[b];
    const int end  = base + cnt;

    if (tid < 256) hist[tid] = 0;
    __syncthreads();

    for (int i = base + tid; i < end; i += 512)
        atomicAdd(&hist[sedge[i] >> 16], 1);
    __syncthreads();

    int v = 0, iv = 0;
    if (tid < 256) {                        // waves 0..3 entirely (wave-uniform branch)
        v = hist[tid];
        iv = wscan64(v, lane);
        if (lane == 63) wsum[wave] = iv;
    }
    __syncthreads();
    if (tid < 256) {
        int add = 0;
#pragma unroll
        for (int w = 0; w < 3; ++w)
            add += (w < wave) ? wsum[w] : 0;
        int excl = iv + add - v;
        cur[tid] = excl;
        int col0 = b << 8;
        int ncol = min(256, N_NODES - col0);
        if (tid < ncol) {
            off[col0 + tid] = base + excl;
            dinv[col0 + tid] = rsqrtf((float)(v + 1));   // +1 self-loop
        }
    }
    if (b == NB - 1 && tid == 0) off[N_NODES] = N_EDGES;
    __syncthreads();

    if (cnt <= SORT_STAGE) {
        // stage in LDS at local offset, then contiguous coalesced flush
        for (int i = base + tid; i < end; i += 512) {
            unsigned e = sedge[i];
            int p = atomicAdd(&cur[e >> 16], 1);
            st[p] = (unsigned short)e;
        }
        __syncthreads();
        for (int i = tid; i < cnt; i += 512)
            sorted[base + i] = st[i];
    } else {
        // fallback (practically never: expected max bucket ~8.5K << 10240)
        for (int i = base + tid; i < end; i += 512) {
            unsigned e = sedge[i];
            int p = atomicAdd(&cur[e >> 16], 1);
            sorted[base + p] = (unsigned short)e;
        }
    }
}

// ---------------- GEMM1 v2 (f16 MFMA): 64x64 tile, double-buffered LDS, reg prefetch ----------
// hs1[i,j] = f16((x[i,:] @ W1[:,j]) * dinv[i]); 625 blocks, 1 barrier per K-iter.

#define LDA 72
#define LDB 72

__global__ __launch_bounds__(256) void k_gemm1(const float* __restrict__ X,
                                               const _Float16* __restrict__ Wt,
                                               const float* __restrict__ dinv,
                                               _Float16* __restrict__ out) {
    __shared__ _Float16 As[2][64 * LDA];
    __shared__ _Float16 Bs[2][64 * LDB];
    const int tid = threadIdx.x;
    const int wave = tid >> 6, lane = tid & 63;
    const int row0 = blockIdx.x * 64;
    const int m0 = (wave & 1) * 32, n0 = (wave >> 1) * 32;
    const int lr = lane & 15, quad = lane >> 4;

    const int ar = tid >> 2;          // 0..63 A row
    const int ak = (tid & 3) * 16;    // K offset (16 floats, 64 B contiguous)
    const int bn = tid >> 2;          // 0..63 B row (n)
    const int bk = (tid & 3) * 16;    // K offset (16 halves)

    f32x4 acc00 = {0.f,0.f,0.f,0.f}, acc01 = {0.f,0.f,0.f,0.f};
    f32x4 acc10 = {0.f,0.f,0.f,0.f}, acc11 = {0.f,0.f,0.f,0.f};

    float4 xv0, xv1, xv2, xv3;
    uint4 wv0, wv1;

#define GLOAD(K0) {                                                          \
        const float4* xp = (const float4*)&X[(row0 + ar) * D_FEAT + (K0) + ak]; \
        xv0 = xp[0]; xv1 = xp[1]; xv2 = xp[2]; xv3 = xp[3];                  \
        const uint4* wp = (const uint4*)&Wt[bn * D_FEAT + (K0) + bk];        \
        wv0 = wp[0]; wv1 = wp[1]; }

#define LSTORE(B) {                                                          \
        f16x8 p0 = {(_Float16)xv0.x,(_Float16)xv0.y,(_Float16)xv0.z,(_Float16)xv0.w, \
                    (_Float16)xv1.x,(_Float16)xv1.y,(_Float16)xv1.z,(_Float16)xv1.w}; \
        f16x8 p1 = {(_Float16)xv2.x,(_Float16)xv2.y,(_Float16)xv2.z,(_Float16)xv2.w, \
                    (_Float16)xv3.x,(_Float16)xv3.y,(_Float16)xv3.z,(_Float16)xv3.w}; \
        *(f16x8*)&As[B][ar * LDA + ak]     = p0;                             \
        *(f16x8*)&As[B][ar * LDA + ak + 8] = p1;                             \
        *(uint4*)&Bs[B][bn * LDB + bk]     = wv0;                            \
        *(uint4*)&Bs[B][bn * LDB + bk + 8] = wv1; }

#define MFMA_STEP(B) {                                                       \
        _Pragma("unroll")                                                    \
        for (int kk = 0; kk < 64; kk += 32) {                                \
            f16x8 a0 = *(f16x8*)&As[B][(m0 + lr) * LDA + kk + quad * 8];     \
            f16x8 a1 = *(f16x8*)&As[B][(m0 + 16 + lr) * LDA + kk + quad * 8];\
            f16x8 b0 = *(f16x8*)&Bs[B][(n0 + lr) * LDB + kk + quad * 8];     \
            f16x8 b1 = *(f16x8*)&Bs[B][(n0 + 16 + lr) * LDB + kk + quad * 8];\
            acc00 = __builtin_amdgcn_mfma_f32_16x16x32_f16(a0, b0, acc00, 0, 0, 0); \
            acc01 = __builtin_amdgcn_mfma_f32_16x16x32_f16(a0, b1, acc01, 0, 0, 0); \
            acc10 = __builtin_amdgcn_mfma_f32_16x16x32_f16(a1, b0, acc10, 0, 0, 0); \
            acc11 = __builtin_amdgcn_mfma_f32_16x16x32_f16(a1, b1, acc11, 0, 0, 0); \
        } }

    GLOAD(0);
    LSTORE(0);
    __syncthreads();
    int buf = 0;
    for (int k0 = 64; k0 < D_FEAT; k0 += 64) {
        GLOAD(k0);              // issue next-tile loads early (hide under MFMA)
        MFMA_STEP(buf);
        LSTORE(buf ^ 1);        // waits on loads, writes other buffer
        __syncthreads();
        buf ^= 1;
    }
    MFMA_STEP(buf);

#pragma unroll
    for (int r = 0; r < 4; ++r) {
        int m = row0 + m0 + quad * 4 + r;
        float dv0 = dinv[m], dv1 = dinv[m + 16];
        out[m * HIDDEN + n0 + lr]             = (_Float16)(acc00[r] * dv0);
        out[m * HIDDEN + n0 + 16 + lr]        = (_Float16)(acc01[r] * dv0);
        out[(m + 16) * HIDDEN + n0 + lr]      = (_Float16)(acc10[r] * dv1);
        out[(m + 16) * HIDDEN + n0 + 16 + lr] = (_Float16)(acc11[r] * dv1);
    }
#undef GLOAD
#undef LSTORE
#undef MFMA_STEP
}

// ---------------- gather1: A1[node] = f16( dinv * relu(dinv * agg(B1) + b1) ) ----------------

__global__ __launch_bounds__(256) void k_agg1(const int* __restrict__ off,
                                              const unsigned short* __restrict__ sorted,
                                              const _Float16* __restrict__ hs,
                                              const float* __restrict__ dinv,
                                              const float* __restrict__ bias,
                                              _Float16* __restrict__ A1) {
    const int tid = threadIdx.x;
    const int wave = tid >> 6, lane = tid & 63;
    const int node = blockIdx.x * 4 + wave;
    const int g = lane >> 3;      // edge slot within a 16-edge step
    const int sl = lane & 7;      // feature slice (8 f16 = 16 B)

    float acc[8];
#pragma unroll
    for (int j = 0; j < 8; ++j) acc[j] = 0.f;
    if (g == 0) {                 // self-loop counted exactly once (group 0)
        f16x8 v = *(const f16x8*)&hs[node * HIDDEN + sl * 8];
#pragma unroll
        for (int j = 0; j < 8; ++j) acc[j] = (float)v[j];
    }

    const int beg = off[node], end = off[node + 1];
    for (int base = beg; base < end; base += 64) {
        int m = end - base; if (m > 64) m = 64;
        int vidx = (lane < m) ? (int)sorted[base + lane] : 0;
        int nfull = m & ~15;
        int i = 0;
        for (; i < nfull; i += 16) {          // 16 edges, 2 loads/lane in flight
            int s0 = __shfl(vidx, i + g, 64);
            int s1 = __shfl(vidx, i + 8 + g, 64);
            f16x8 v0 = *(const f16x8*)&hs[s0 * HIDDEN + sl * 8];
            f16x8 v1 = *(const f16x8*)&hs[s1 * HIDDEN + sl * 8];
            f16x8 t = v0 + v1;                // v_pk_add_f16 x4
#pragma unroll
            for (int j = 0; j < 8; ++j)
                acc[j] += (float)t[j];
        }
        if (i < m) {                          // masked tail (<16 edges)
            int s0 = __shfl(vidx, i + g, 64);
            int s1 = __shfl(vidx, i + 8 + g, 64);   // i+8+g <= 63 always
            f16x8 v0 = {};
            f16x8 v1 = {};
            if (i + g < m)     v0 = *(const f16x8*)&hs[s0 * HIDDEN + sl * 8];
            if (i + 8 + g < m) v1 = *(const f16x8*)&hs[s1 * HIDDEN + sl * 8];
            f16x8 t = v0 + v1;
#pragma unroll
            for (int j = 0; j < 8; ++j)
                acc[j] += (float)t[j];
        }
    }

    // fold the 8 edge-groups (bits 3..5 of lane)
#pragma unroll
    for (int j = 0; j < 8; ++j) {
        acc[j] += __shfl_xor(acc[j], 8, 64);
        acc[j] += __shfl_xor(acc[j], 16, 64);
        acc[j] += __shfl_xor(acc[j], 32, 64);
    }
    if (lane < 8) {
        float dv = dinv[node];
        f16x8 o;
#pragma unroll
        for (int j = 0; j < 8; ++j) {
            float z = fmaf(dv, acc[j], bias[lane * 8 + j]);
            o[j] = (_Float16)(fmaxf(z, 0.f) * dv);   // pre-scale for layer-2 source norm
        }
        *(f16x8*)&A1[node * HIDDEN + lane * 8] = o;
    }
}

// ---------------- gather2 + GEMV(64x40) + log-softmax ----------------
// linearity: Agg(norm * (a1 @ W2)) == Agg(norm * a1) @ W2

__global__ __launch_bounds__(256) void k_agg2_lsm(const int* __restrict__ off,
                                                  const unsigned short* __restrict__ sorted,
                                                  const _Float16* __restrict__ A1,
                                                  const float* __restrict__ dinv,
                                                  const float* __restrict__ b2,
                                                  const float* __restrict__ W2,
                                                  float* __restrict__ out) {
    __shared__ float W2s[HIDDEN * N_CLASSES];   // [k][c], as given
    __shared__ float aggs[4][HIDDEN];
    const int tid = threadIdx.x;
    for (int i = tid; i < HIDDEN * N_CLASSES; i += 256) W2s[i] = W2[i];
    const int wave = tid >> 6, lane = tid & 63;
    const int node = blockIdx.x * 4 + wave;
    const int g = lane >> 3, sl = lane & 7;

    float acc[8];
#pragma unroll
    for (int j = 0; j < 8; ++j) acc[j] = 0.f;
    if (g == 0) {
        f16x8 v = *(const f16x8*)&A1[node * HIDDEN + sl * 8];
#pragma unroll
        for (int j = 0; j < 8; ++j) acc[j] = (float)v[j];
    }
    __syncthreads();   // W2s staged; placed before divergent-length gather

    const int beg = off[node], end = off[node + 1];
    for (int base = beg; base < end; base += 64) {
        int m = end - base; if (m > 64) m = 64;
        int vidx = (lane < m) ? (int)sorted[base + lane] : 0;
        int nfull = m & ~15;
        int i = 0;
        for (; i < nfull; i += 16) {
            int s0 = __shfl(vidx, i + g, 64);
            int s1 = __shfl(vidx, i + 8 + g, 64);
            f16x8 v0 = *(const f16x8*)&A1[s0 * HIDDEN + sl * 8];
            f16x8 v1 = *(const f16x8*)&A1[s1 * HIDDEN + sl * 8];
            f16x8 t = v0 + v1;
#pragma unroll
            for (int j = 0; j < 8; ++j)
                acc[j] += (float)t[j];
        }
        if (i < m) {
            int s0 = __shfl(vidx, i + g, 64);
            int s1 = __shfl(vidx, i + 8 + g, 64);
            f16x8 v0 = {};
            f16x8 v1 = {};
            if (i + g < m)     v0 = *(const f16x8*)&A1[s0 * HIDDEN + sl * 8];
            if (i + 8 + g < m) v1 = *(const f16x8*)&A1[s1 * HIDDEN + sl * 8];
            f16x8 t = v0 + v1;
#pragma unroll
            for (int j = 0; j < 8; ++j)
                acc[j] += (float)t[j];
        }
    }
#pragma unroll
    for (int j = 0; j < 8; ++j) {
        acc[j] += __shfl_xor(acc[j], 8, 64);
        acc[j] += __shfl_xor(acc[j], 16, 64);
        acc[j] += __shfl_xor(acc[j], 32, 64);
    }
    if (lane < 8) {
        f32x4 t0 = {acc[0], acc[1], acc[2], acc[3]};
        f32x4 t1 = {acc[4], acc[5], acc[6], acc[7]};
        *(f32x4*)&aggs[wave][lane * 8]     = t0;
        *(f32x4*)&aggs[wave][lane * 8 + 4] = t1;
    }
    __builtin_amdgcn_wave_barrier();   // same-wave LDS write->read ordering fence

    float z = -INFINITY;
    if (lane < N_CLASSES) {
        float s = 0.f;
        const float* ag = aggs[wave];
#pragma unroll
        for (int k = 0; k < HIDDEN; ++k)
            s = fmaf(ag[k], W2s[k * N_CLASSES + lane], s);
        z = fmaf(dinv[node], s, b2[lane]);
    }
    float mv = z;
#pragma unroll
    for (int d = 32; d > 0; d >>= 1) mv = fmaxf(mv, __shfl_xor(mv, d, 64));
    float ex = (lane < N_CLASSES) ? expf(z - mv) : 0.f;
#pragma unroll
    for (int d = 32; d > 0; d >>= 1) ex += __shfl_xor(ex, d, 64);
    float lse = mv + logf(ex);
    if (lane < N_CLASSES) out[node * N_CLASSES + lane] = z - lse;
}

// ---------------- launch ----------------

extern "C" void kernel_launch(void* const* d_in, const int* in_sizes, int n_in,
                              void* d_out, int out_size, void* d_ws, size_t ws_size,
                              hipStream_t stream) {
    const float* x  = (const float*)d_in[0];
    const int*   ei = (const int*)d_in[1];
    const float* W1 = (const float*)d_in[2];
    const float* b1 = (const float*)d_in[3];
    const float* W2 = (const float*)d_in[4];
    const float* b2 = (const float*)d_in[5];
    const int* row = ei;             // edge_index[0] = source
    const int* col = ei + N_EDGES;   // edge_index[1] = target

    char* ws = (char*)d_ws;
    int*            btot   = (int*)(ws + 0);             // 628 B
    int*            gcur   = (int*)(ws + 1024);          // 628 B
    int*            bb     = (int*)(ws + 2048);          // 628 B
    int*            off    = (int*)(ws + 4096);          // 160 KB + 4
    float*          dinv   = (float*)(ws + 167936);      // 160 KB
    unsigned*       sedge  = (unsigned*)(ws + 335872);   // 5.12 MB (dead after bucketsort)
    unsigned short* sorted = (unsigned short*)(ws + 5455872); // 2.56 MB
    _Float16*       W1t    = (_Float16*)(ws + 8015872);  // 128 KB
    _Float16*       B1     = (_Float16*)(ws + 8146944);  // 5.12 MB : hs1 f16
    _Float16*       A1     = (_Float16*)(ws + 335872);   // 5.12 MB : reuse sedge slot

    hipMemsetAsync(btot, 0, 2048, stream);   // btot + gcur
    k_pre<<<HIST_BLOCKS + CONV_BLOCKS, 256, 0, stream>>>(col, btot, W1, W1t);
    k_scanbb<<<1, 256, 0, stream>>>(btot, bb);
    k_binscatter<<<N_EDGES / CHUNK, 256, 0, stream>>>(row, col, bb, gcur, sedge);
    k_bucketsort<<<NB, 512, 0, stream>>>(sedge, btot, bb, off, dinv, sorted);

    k_gemm1<<<N_NODES / 64, 256, 0, stream>>>(x, W1t, dinv, B1);
    k_agg1<<<N_NODES / 4, 256, 0, stream>>>(off, sorted, B1, dinv, b1, A1);
    k_agg2_lsm<<<N_NODES / 4, 256, 0, stream>>>(off, sorted, A1, dinv, b2, W2, (float*)d_out);
}

// Round 6
// 355.650 us; speedup vs baseline: 1.5022x; 1.0413x over previous
//
#include <hip/hip_runtime.h>
#include <hip/hip_bf16.h>
#include <math.h>

#define N_NODES 40000
#define N_EDGES 1280000
#define D_FEAT 1024
#define HIDDEN 64
#define N_CLASSES 40
#define NB 157            // buckets of 256 destination cols
#define CHUNK 2048        // edges per binscatter block (625*2048 == N_EDGES)
#define SORT_STAGE 10240  // u16 staging in bucketsort (expected max bucket ~8500)
#define GEMM_BLOCKS 625   // N_NODES/64
#define GEMM_A 312        // gemm blocks in phase 0
#define GEMM_B 313        // gemm blocks in phase 1

typedef _Float16 f16x8 __attribute__((ext_vector_type(8)));
typedef float f32x4 __attribute__((ext_vector_type(4)));

__device__ __forceinline__ int wscan64(int v, int lane) {
#pragma unroll
    for (int d = 1; d < 64; d <<= 1) {
        int t = __shfl_up(v, d, 64);
        v += (lane >= d) ? t : 0;
    }
    return v;
}

// ---------------- pass 0: bucket histogram (int4) + W1 transpose/convert ----------------

#define HIST_BLOCKS 313
#define CONV_BLOCKS 256

__global__ __launch_bounds__(256) void k_pre(const int* __restrict__ col,
                                             int* __restrict__ btot,
                                             const float* __restrict__ W,
                                             _Float16* __restrict__ Wt) {
    __shared__ int h[NB];
    int tid = threadIdx.x;
    if (blockIdx.x < HIST_BLOCKS) {
        if (tid < NB) h[tid] = 0;
        __syncthreads();
        int e0 = blockIdx.x * 4096;
#pragma unroll
        for (int t = 0; t < 4; ++t) {
            int e = e0 + t * 1024 + tid * 4;
            if (e < N_EDGES) {
                int4 c = *(const int4*)&col[e];
                atomicAdd(&h[c.x >> 8], 1);
                atomicAdd(&h[c.y >> 8], 1);
                atomicAdd(&h[c.z >> 8], 1);
                atomicAdd(&h[c.w >> 8], 1);
            }
        }
        __syncthreads();
        if (tid < NB && h[tid]) atomicAdd(&btot[tid], h[tid]);
    } else {
        int i = (blockIdx.x - HIST_BLOCKS) * 256 + tid;
        int n = i & 63, k = i >> 6;
        Wt[n * D_FEAT + k] = (_Float16)W[k * HIDDEN + n];
    }
}

// ---------------- shared-memory overlays for the mixed kernel ----------------

struct BinS {                       // ~12.8 KB
    unsigned stage[CHUNK];
    unsigned char bo[CHUNK];
    int hist[NB]; int lo[NB]; int cur[NB]; int dst[NB];
    int wsA[4]; int wsB[4];
};
struct SortS {                      // ~22.6 KB
    int hist[256]; int cur[256];
    unsigned short st[SORT_STAGE];
    int ws[4];
    int sbase, scnt;
};
#define GEMM_SMEM 36864             // As[2][64*72] + Bs[2][64*72], f16

// ---------------- binscatter body (inline bucket-base scan) ----------------

__device__ __forceinline__ void binscatter_body(char* smem, int bx,
        const int* __restrict__ row, const int* __restrict__ col,
        const int* __restrict__ btot, int* __restrict__ gcur,
        unsigned* __restrict__ sedge, int tid, int wave, int lane) {
    BinS* S = (BinS*)smem;
    const int e0 = bx * CHUNK;
    if (tid < NB) { S->hist[tid] = 0; S->cur[tid] = 0; }
    int bv = (tid < NB) ? btot[tid] : 0;
    int ivb = wscan64(bv, lane);
    if (lane == 63) S->wsB[wave] = ivb;
    __syncthreads();
    int addb = 0;
#pragma unroll
    for (int w = 0; w < 3; ++w) addb += (w < wave) ? S->wsB[w] : 0;
    int bbv = ivb + addb - bv;          // exclusive global bucket base (tid<NB)

    int c[8];
#pragma unroll
    for (int t = 0; t < 8; ++t) {
        int e = tid + t * 256;
        c[t] = col[e0 + e];
        atomicAdd(&S->hist[c[t] >> 8], 1);
    }
    __syncthreads();

    int hv = (tid < NB) ? S->hist[tid] : 0;
    int iv = wscan64(hv, lane);
    if (lane == 63) S->wsA[wave] = iv;
    __syncthreads();
    int add = 0;
#pragma unroll
    for (int w = 0; w < 3; ++w) add += (w < wave) ? S->wsA[w] : 0;
    if (tid < NB) {
        int excl = iv + add - hv;
        S->lo[tid] = excl;
        int cp = hv ? atomicAdd(&gcur[tid], hv) : 0;
        S->dst[tid] = bbv + cp - excl;
    }
    __syncthreads();

#pragma unroll
    for (int t = 0; t < 8; ++t) {
        int e = tid + t * 256;
        int b = c[t] >> 8;
        int p = S->lo[b] + atomicAdd(&S->cur[b], 1);
        S->stage[p] = ((unsigned)(c[t] & 255) << 16) | (unsigned)row[e0 + e];
        S->bo[p] = (unsigned char)b;
    }
    __syncthreads();
    for (int i = tid; i < CHUNK; i += 256)
        sedge[S->dst[S->bo[i]] + i] = S->stage[i];
}

// ---------------- bucketsort body (256 thr, inline base scan, staged flush) ----------------

__device__ __forceinline__ void sort_body(char* smem, int b,
        const unsigned* __restrict__ sedge, const int* __restrict__ btot,
        int* __restrict__ off, float* __restrict__ dinv,
        unsigned short* __restrict__ sorted, int tid, int wave, int lane) {
    SortS* S = (SortS*)smem;
    S->hist[tid] = 0;
    int bv = (tid < NB) ? btot[tid] : 0;
    int ivb = wscan64(bv, lane);
    if (lane == 63) S->ws[wave] = ivb;
    __syncthreads();
    int addb = 0;
#pragma unroll
    for (int w = 0; w < 3; ++w) addb += (w < wave) ? S->ws[w] : 0;
    if (tid == b) { S->sbase = ivb + addb - bv; S->scnt = bv; }
    __syncthreads();
    const int base = S->sbase, cnt = S->scnt, end = base + cnt;

    for (int i = base + tid; i < end; i += 256)
        atomicAdd(&S->hist[sedge[i] >> 16], 1);
    __syncthreads();
    int v = S->hist[tid];
    int iv = wscan64(v, lane);
    if (lane == 63) S->ws[wave] = iv;
    __syncthreads();
    int add = 0;
#pragma unroll
    for (int w = 0; w < 3; ++w) add += (w < wave) ? S->ws[w] : 0;
    int excl = iv + add - v;
    S->cur[tid] = excl;
    int col0 = b << 8;
    int ncol = min(256, N_NODES - col0);
    if (tid < ncol) {
        off[col0 + tid] = base + excl;
        dinv[col0 + tid] = rsqrtf((float)(v + 1));   // +1 self-loop
    }
    if (b == NB - 1 && tid == 0) off[N_NODES] = N_EDGES;
    __syncthreads();

    if (cnt <= SORT_STAGE) {
        for (int i = base + tid; i < end; i += 256) {
            unsigned e = sedge[i];
            int p = atomicAdd(&S->cur[e >> 16], 1);
            S->st[p] = (unsigned short)e;
        }
        __syncthreads();
        for (int i = tid; i < cnt; i += 256)
            sorted[base + i] = S->st[i];
    } else {
        for (int i = base + tid; i < end; i += 256) {
            unsigned e = sedge[i];
            int p = atomicAdd(&S->cur[e >> 16], 1);
            sorted[base + p] = (unsigned short)e;
        }
    }
}

// ---------------- gemm body: B1[i,j] = f16(x[i,:] @ W1[:,j])  (NO dinv — moved to agg1) ----

#define LDA 72
#define LDB 72

__device__ __forceinline__ void gemm_body(char* smem, int bx,
        const float* __restrict__ X, const _Float16* __restrict__ Wt,
        _Float16* __restrict__ out, int tid) {
    auto As = (_Float16(*)[64 * LDA])(smem);
    auto Bs = (_Float16(*)[64 * LDB])(smem + 2 * 64 * LDA * 2);
    const int wave = tid >> 6, lane = tid & 63;
    const int row0 = bx * 64;
    const int m0 = (wave & 1) * 32, n0 = (wave >> 1) * 32;
    const int lr = lane & 15, quad = lane >> 4;

    const int ar = tid >> 2;
    const int ak = (tid & 3) * 16;
    const int bn = tid >> 2;
    const int bk = (tid & 3) * 16;

    f32x4 acc00 = {0.f,0.f,0.f,0.f}, acc01 = {0.f,0.f,0.f,0.f};
    f32x4 acc10 = {0.f,0.f,0.f,0.f}, acc11 = {0.f,0.f,0.f,0.f};

    float4 xv0, xv1, xv2, xv3;
    uint4 wv0, wv1;

#define GLOAD(K0) {                                                          \
        const float4* xp = (const float4*)&X[(row0 + ar) * D_FEAT + (K0) + ak]; \
        xv0 = xp[0]; xv1 = xp[1]; xv2 = xp[2]; xv3 = xp[3];                  \
        const uint4* wp = (const uint4*)&Wt[bn * D_FEAT + (K0) + bk];        \
        wv0 = wp[0]; wv1 = wp[1]; }

#define LSTORE(B) {                                                          \
        f16x8 p0 = {(_Float16)xv0.x,(_Float16)xv0.y,(_Float16)xv0.z,(_Float16)xv0.w, \
                    (_Float16)xv1.x,(_Float16)xv1.y,(_Float16)xv1.z,(_Float16)xv1.w}; \
        f16x8 p1 = {(_Float16)xv2.x,(_Float16)xv2.y,(_Float16)xv2.z,(_Float16)xv2.w, \
                    (_Float16)xv3.x,(_Float16)xv3.y,(_Float16)xv3.z,(_Float16)xv3.w}; \
        *(f16x8*)&As[B][ar * LDA + ak]     = p0;                             \
        *(f16x8*)&As[B][ar * LDA + ak + 8] = p1;                             \
        *(uint4*)&Bs[B][bn * LDB + bk]     = wv0;                            \
        *(uint4*)&Bs[B][bn * LDB + bk + 8] = wv1; }

#define MFMA_STEP(B) {                                                       \
        _Pragma("unroll")                                                    \
        for (int kk = 0; kk < 64; kk += 32) {                                \
            f16x8 a0 = *(f16x8*)&As[B][(m0 + lr) * LDA + kk + quad * 8];     \
            f16x8 a1 = *(f16x8*)&As[B][(m0 + 16 + lr) * LDA + kk + quad * 8];\
            f16x8 b0 = *(f16x8*)&Bs[B][(n0 + lr) * LDB + kk + quad * 8];     \
            f16x8 b1 = *(f16x8*)&Bs[B][(n0 + 16 + lr) * LDB + kk + quad * 8];\
            acc00 = __builtin_amdgcn_mfma_f32_16x16x32_f16(a0, b0, acc00, 0, 0, 0); \
            acc01 = __builtin_amdgcn_mfma_f32_16x16x32_f16(a0, b1, acc01, 0, 0, 0); \
            acc10 = __builtin_amdgcn_mfma_f32_16x16x32_f16(a1, b0, acc10, 0, 0, 0); \
            acc11 = __builtin_amdgcn_mfma_f32_16x16x32_f16(a1, b1, acc11, 0, 0, 0); \
        } }

    GLOAD(0);
    LSTORE(0);
    __syncthreads();
    int buf = 0;
    for (int k0 = 64; k0 < D_FEAT; k0 += 64) {
        GLOAD(k0);
        MFMA_STEP(buf);
        LSTORE(buf ^ 1);
        __syncthreads();
        buf ^= 1;
    }
    MFMA_STEP(buf);

#pragma unroll
    for (int r = 0; r < 4; ++r) {
        int m = row0 + m0 + quad * 4 + r;
        out[m * HIDDEN + n0 + lr]             = (_Float16)acc00[r];
        out[m * HIDDEN + n0 + 16 + lr]        = (_Float16)acc01[r];
        out[(m + 16) * HIDDEN + n0 + lr]      = (_Float16)acc10[r];
        out[(m + 16) * HIDDEN + n0 + 16 + lr] = (_Float16)acc11[r];
    }
#undef GLOAD
#undef LSTORE
#undef MFMA_STEP
}

// ---------------- mixed dispatches: preprocessing ∥ gemm ----------------
// phase 0: blocks [0,625) binscatter | [625,937) gemm rows 0..311
// phase 1: blocks [0,157) bucketsort | [157,470) gemm rows 312..624

__global__ __launch_bounds__(256) void k_mix(int phase,
        const int* __restrict__ row, const int* __restrict__ col,
        const int* __restrict__ btot, int* __restrict__ gcur,
        unsigned* __restrict__ sedge,
        int* __restrict__ off, float* __restrict__ dinv,
        unsigned short* __restrict__ sorted,
        const float* __restrict__ X, const _Float16* __restrict__ Wt,
        _Float16* __restrict__ B1) {
    __shared__ __align__(16) char smem[GEMM_SMEM];
    const int tid = threadIdx.x;
    const int wave = tid >> 6, lane = tid & 63;
    if (phase == 0) {
        if (blockIdx.x < 625)
            binscatter_body(smem, blockIdx.x, row, col, btot, gcur, sedge, tid, wave, lane);
        else
            gemm_body(smem, (int)blockIdx.x - 625, X, Wt, B1, tid);
    } else {
        if (blockIdx.x < NB)
            sort_body(smem, blockIdx.x, sedge, btot, off, dinv, sorted, tid, wave, lane);
        else
            gemm_body(smem, (int)blockIdx.x - NB + GEMM_A, X, Wt, B1, tid);
    }
}

// ---------------- gather1: per-edge f16 dinv[src] scale packed into the shfl word ----------
// A1[node] = f16( dinv[node] * relu( dinv[node]*(Σ_s dinv[s]·h[s] + dinv[node]·h[node]) + b1 ) )

__global__ __launch_bounds__(256) void k_agg1(const int* __restrict__ off,
                                              const unsigned short* __restrict__ sorted,
                                              const _Float16* __restrict__ hs,
                                              const float* __restrict__ dinv,
                                              const float* __restrict__ bias,
                                              _Float16* __restrict__ A1) {
    const int tid = threadIdx.x;
    const int wave = tid >> 6, lane = tid & 63;
    const int node = blockIdx.x * 4 + wave;
    const int g = lane >> 3;
    const int sl = lane & 7;

    float acc[8];
#pragma unroll
    for (int j = 0; j < 8; ++j) acc[j] = 0.f;
    if (g == 0) {                 // self-loop: dinv[node]·h[node]
        float dvn = dinv[node];
        f16x8 v = *(const f16x8*)&hs[node * HIDDEN + sl * 8];
#pragma unroll
        for (int j = 0; j < 8; ++j) acc[j] = (float)v[j] * dvn;
    }

    const int beg = off[node], end = off[node + 1];
    for (int base = beg; base < end; base += 64) {
        int m = end - base; if (m > 64) m = 64;
        unsigned pk = 0;
        if (lane < m) {
            int vv = (int)sorted[base + lane];
            _Float16 dvh = (_Float16)dinv[vv];
            pk = (unsigned)vv | ((unsigned)__builtin_bit_cast(unsigned short, dvh) << 16);
        }
        int nfull = m & ~15;
        int i = 0;
        for (; i < nfull; i += 16) {
            unsigned p0 = (unsigned)__shfl((int)pk, i + g, 64);
            unsigned p1 = (unsigned)__shfl((int)pk, i + 8 + g, 64);
            const f16x8 v0 = *(const f16x8*)&hs[(p0 & 0xffffu) * HIDDEN + sl * 8];
            const f16x8 v1 = *(const f16x8*)&hs[(p1 & 0xffffu) * HIDDEN + sl * 8];
            _Float16 d0 = __builtin_bit_cast(_Float16, (unsigned short)(p0 >> 16));
            _Float16 d1 = __builtin_bit_cast(_Float16, (unsigned short)(p1 >> 16));
            f16x8 t = v0 * d0 + v1 * d1;      // pk_mul/pk_fma
#pragma unroll
            for (int j = 0; j < 8; ++j)
                acc[j] += (float)t[j];
        }
        if (i < m) {
            unsigned p0 = (unsigned)__shfl((int)pk, i + g, 64);
            unsigned p1 = (unsigned)__shfl((int)pk, i + 8 + g, 64);
            f16x8 v0 = {}, v1 = {};
            _Float16 d0 = (_Float16)0.f, d1 = (_Float16)0.f;
            if (i + g < m) {
                v0 = *(const f16x8*)&hs[(p0 & 0xffffu) * HIDDEN + sl * 8];
                d0 = __builtin_bit_cast(_Float16, (unsigned short)(p0 >> 16));
            }
            if (i + 8 + g < m) {
                v1 = *(const f16x8*)&hs[(p1 & 0xffffu) * HIDDEN + sl * 8];
                d1 = __builtin_bit_cast(_Float16, (unsigned short)(p1 >> 16));
            }
            f16x8 t = v0 * d0 + v1 * d1;
#pragma unroll
            for (int j = 0; j < 8; ++j)
                acc[j] += (float)t[j];
        }
    }

#pragma unroll
    for (int j = 0; j < 8; ++j) {
        acc[j] += __shfl_xor(acc[j], 8, 64);
        acc[j] += __shfl_xor(acc[j], 16, 64);
        acc[j] += __shfl_xor(acc[j], 32, 64);
    }
    if (lane < 8) {
        float dv = dinv[node];
        f16x8 o;
#pragma unroll
        for (int j = 0; j < 8; ++j) {
            float z = fmaf(dv, acc[j], bias[lane * 8 + j]);
            o[j] = (_Float16)(fmaxf(z, 0.f) * dv);   // pre-scale for layer-2 source norm
        }
        *(f16x8*)&A1[node * HIDDEN + lane * 8] = o;
    }
}

// ---------------- gather2 + GEMV(64x40) + log-softmax (unchanged) ----------------

__global__ __launch_bounds__(256) void k_agg2_lsm(const int* __restrict__ off,
                                                  const unsigned short* __restrict__ sorted,
                                                  const _Float16* __restrict__ A1,
                                                  const float* __restrict__ dinv,
                                                  const float* __restrict__ b2,
                                                  const float* __restrict__ W2,
                                                  float* __restrict__ out) {
    __shared__ float W2s[HIDDEN * N_CLASSES];
    __shared__ float aggs[4][HIDDEN];
    const int tid = threadIdx.x;
    for (int i = tid; i < HIDDEN * N_CLASSES; i += 256) W2s[i] = W2[i];
    const int wave = tid >> 6, lane = tid & 63;
    const int node = blockIdx.x * 4 + wave;
    const int g = lane >> 3, sl = lane & 7;

    float acc[8];
#pragma unroll
    for (int j = 0; j < 8; ++j) acc[j] = 0.f;
    if (g == 0) {
        f16x8 v = *(const f16x8*)&A1[node * HIDDEN + sl * 8];
#pragma unroll
        for (int j = 0; j < 8; ++j) acc[j] = (float)v[j];
    }
    __syncthreads();

    const int beg = off[node], end = off[node + 1];
    for (int base = beg; base < end; base += 64) {
        int m = end - base; if (m > 64) m = 64;
        int vidx = (lane < m) ? (int)sorted[base + lane] : 0;
        int nfull = m & ~15;
        int i = 0;
        for (; i < nfull; i += 16) {
            int s0 = __shfl(vidx, i + g, 64);
            int s1 = __shfl(vidx, i + 8 + g, 64);
            f16x8 v0 = *(const f16x8*)&A1[s0 * HIDDEN + sl * 8];
            f16x8 v1 = *(const f16x8*)&A1[s1 * HIDDEN + sl * 8];
            f16x8 t = v0 + v1;
#pragma unroll
            for (int j = 0; j < 8; ++j)
                acc[j] += (float)t[j];
        }
        if (i < m) {
            int s0 = __shfl(vidx, i + g, 64);
            int s1 = __shfl(vidx, i + 8 + g, 64);
            f16x8 v0 = {};
            f16x8 v1 = {};
            if (i + g < m)     v0 = *(const f16x8*)&A1[s0 * HIDDEN + sl * 8];
            if (i + 8 + g < m) v1 = *(const f16x8*)&A1[s1 * HIDDEN + sl * 8];
            f16x8 t = v0 + v1;
#pragma unroll
            for (int j = 0; j < 8; ++j)
                acc[j] += (float)t[j];
        }
    }
#pragma unroll
    for (int j = 0; j < 8; ++j) {
        acc[j] += __shfl_xor(acc[j], 8, 64);
        acc[j] += __shfl_xor(acc[j], 16, 64);
        acc[j] += __shfl_xor(acc[j], 32, 64);
    }
    if (lane < 8) {
        f32x4 t0 = {acc[0], acc[1], acc[2], acc[3]};
        f32x4 t1 = {acc[4], acc[5], acc[6], acc[7]};
        *(f32x4*)&aggs[wave][lane * 8]     = t0;
        *(f32x4*)&aggs[wave][lane * 8 + 4] = t1;
    }
    __builtin_amdgcn_wave_barrier();

    float z = -INFINITY;
    if (lane < N_CLASSES) {
        float s = 0.f;
        const float* ag = aggs[wave];
#pragma unroll
        for (int k = 0; k < HIDDEN; ++k)
            s = fmaf(ag[k], W2s[k * N_CLASSES + lane], s);
        z = fmaf(dinv[node], s, b2[lane]);
    }
    float mv = z;
#pragma unroll
    for (int d = 32; d > 0; d >>= 1) mv = fmaxf(mv, __shfl_xor(mv, d, 64));
    float ex = (lane < N_CLASSES) ? expf(z - mv) : 0.f;
#pragma unroll
    for (int d = 32; d > 0; d >>= 1) ex += __shfl_xor(ex, d, 64);
    float lse = mv + logf(ex);
    if (lane < N_CLASSES) out[node * N_CLASSES + lane] = z - lse;
}

// ---------------- launch ----------------

extern "C" void kernel_launch(void* const* d_in, const int* in_sizes, int n_in,
                              void* d_out, int out_size, void* d_ws, size_t ws_size,
                              hipStream_t stream) {
    const float* x  = (const float*)d_in[0];
    const int*   ei = (const int*)d_in[1];
    const float* W1 = (const float*)d_in[2];
    const float* b1 = (const float*)d_in[3];
    const float* W2 = (const float*)d_in[4];
    const float* b2 = (const float*)d_in[5];
    const int* row = ei;             // edge_index[0] = source
    const int* col = ei + N_EDGES;   // edge_index[1] = target

    char* ws = (char*)d_ws;
    int*            btot   = (int*)(ws + 0);             // 628 B
    int*            gcur   = (int*)(ws + 1024);          // 628 B
    int*            off    = (int*)(ws + 4096);          // 160 KB + 4
    float*          dinv   = (float*)(ws + 167936);      // 160 KB
    unsigned*       sedge  = (unsigned*)(ws + 335872);   // 5.12 MB (dead after sort)
    unsigned short* sorted = (unsigned short*)(ws + 5455872); // 2.56 MB
    _Float16*       W1t    = (_Float16*)(ws + 8015872);  // 128 KB
    _Float16*       B1     = (_Float16*)(ws + 8146944);  // 5.12 MB
    _Float16*       A1     = (_Float16*)(ws + 335872);   // 5.12 MB : reuse sedge slot

    hipMemsetAsync(btot, 0, 2048, stream);   // btot + gcur
    k_pre<<<HIST_BLOCKS + CONV_BLOCKS, 256, 0, stream>>>(col, btot, W1, W1t);
    k_mix<<<625 + GEMM_A, 256, 0, stream>>>(0, row, col, btot, gcur, sedge,
                                            off, dinv, sorted, x, W1t, B1);
    k_mix<<<NB + GEMM_B, 256, 0, stream>>>(1, row, col, btot, gcur, sedge,
                                           off, dinv, sorted, x, W1t, B1);
    k_agg1<<<N_NODES / 4, 256, 0, stream>>>(off, sorted, B1, dinv, b1, A1);
    k_agg2_lsm<<<N_NODES / 4, 256, 0, stream>>>(off, sorted, A1, dinv, b2, W2, (float*)d_out);
}